// Round 3
// baseline (659.282 us; speedup 1.0000x reference)
//
#include <hip/hip_runtime.h>

// Problem constants (from reference)
static constexpr int SEQ  = 20;
static constexpr int FEAT = 5;
static constexpr int NU1  = 10;
static constexpr int NU2  = 7;
static constexpr int NU3  = 4;
static constexpr int NOUT = 4;

// Packed-weight layout in d_ws (flat floats):
static constexpr int OWK1 = 0;                    // 5*40   = 200
static constexpr int OWR1 = 200;                  // 10*40  = 400
static constexpr int OB1  = 600;                  // 40
static constexpr int OWK2 = 640;                  // 10*28  = 280
static constexpr int OWR2 = 920;                  // 7*28   = 196
static constexpr int OB2  = 1116;                 // 28
static constexpr int OWK3 = 1144;                 // 7*16   = 112
static constexpr int OWR3 = 1256;                 // 4*16   = 64
static constexpr int OB3  = 1320;                 // 16
static constexpr int OWD  = 1336;                 // 4*4    = 16
static constexpr int OBD  = 1352;                 // 4
static constexpr int NWF  = 1356;                 // total packed floats
static constexpr int NW   = 22;                   // ceil(1408/64) VGPRs holding all weights

// Fast HW transcendentals (v_exp_f32 = 2^x, v_rcp_f32). ~1e-7 rel err.
__device__ __forceinline__ float hexp2(float x) { return __builtin_amdgcn_exp2f(x); }
__device__ __forceinline__ float hrcp(float x)  { return __builtin_amdgcn_rcpf(x); }
__device__ __forceinline__ float sigm(float x) {
    return hrcp(1.0f + hexp2(x * -1.4426950408889634f));
}
__device__ __forceinline__ float ftanh(float x) {
    return 1.0f - 2.0f * hrcp(1.0f + hexp2(x * 2.8853900817779268f));
}

// Broadcast weight #idx from the lane-strided VGPR pack: one v_readlane_b32
// (SALU pipe, co-issues with VALU). idx is compile-time after full unroll.
__device__ __forceinline__ float getw(const float (&w)[NW], int idx) {
    return __uint_as_float(
        __builtin_amdgcn_readlane(__float_as_uint(w[idx >> 6]), idx & 63));
}

// One LSTM timestep; Keras gate order [i, f, g, o]. All weights come from
// the in-register pack via getw -> zero memory ops in the recurrence.
template <int IN, int U, int OWK, int OWR, int OB>
__device__ __forceinline__ void lstm_step(const float (&w)[NW],
                                          const float (&xin)[IN],
                                          float (&h)[U], float (&c)[U]) {
    float hn[U];
#pragma unroll
    for (int u = 0; u < U; ++u) {
        float zi = getw(w, OB + u);
        float zf = getw(w, OB + U + u);
        float zg = getw(w, OB + 2 * U + u);
        float zo = getw(w, OB + 3 * U + u);
#pragma unroll
        for (int f = 0; f < IN; ++f) {
            const float xf = xin[f];
            zi = fmaf(xf, getw(w, OWK + f * 4 * U + 0 * U + u), zi);
            zf = fmaf(xf, getw(w, OWK + f * 4 * U + 1 * U + u), zf);
            zg = fmaf(xf, getw(w, OWK + f * 4 * U + 2 * U + u), zg);
            zo = fmaf(xf, getw(w, OWK + f * 4 * U + 3 * U + u), zo);
        }
#pragma unroll
        for (int k = 0; k < U; ++k) {
            const float hk = h[k];
            zi = fmaf(hk, getw(w, OWR + k * 4 * U + 0 * U + u), zi);
            zf = fmaf(hk, getw(w, OWR + k * 4 * U + 1 * U + u), zf);
            zg = fmaf(hk, getw(w, OWR + k * 4 * U + 2 * U + u), zg);
            zo = fmaf(hk, getw(w, OWR + k * 4 * U + 3 * U + u), zo);
        }
        const float gi = sigm(zi);
        const float gf = sigm(zf);
        const float gg = ftanh(zg);
        const float go = sigm(zo);
        const float cn = gf * c[u] + gi * gg;
        c[u] = cn;
        hn[u] = go * ftanh(cn);
    }
#pragma unroll
    for (int u = 0; u < U; ++u) h[u] = hn[u];
}

// Pre-kernel: pack the 12 weight arrays into d_ws flat (1408 floats, zero pad).
__global__ void pack_weights(const float* __restrict__ Wk1, const float* __restrict__ Wr1,
                             const float* __restrict__ b1,  const float* __restrict__ Wk2,
                             const float* __restrict__ Wr2, const float* __restrict__ b2,
                             const float* __restrict__ Wk3, const float* __restrict__ Wr3,
                             const float* __restrict__ b3,  const float* __restrict__ Wd,
                             const float* __restrict__ bd,  float* __restrict__ ws) {
    const int i = blockIdx.x * blockDim.x + threadIdx.x;
    if (i >= NW * 64) return;
    float v = 0.0f;
    if      (i < OWR1) v = Wk1[i - OWK1];
    else if (i < OB1)  v = Wr1[i - OWR1];
    else if (i < OWK2) v = b1[i - OB1];
    else if (i < OWR2) v = Wk2[i - OWK2];
    else if (i < OB2)  v = Wr2[i - OWR2];
    else if (i < OWK3) v = b2[i - OB2];
    else if (i < OWR3) v = Wk3[i - OWK3];
    else if (i < OB3)  v = Wr3[i - OWR3];
    else if (i < OWD)  v = b3[i - OB3];
    else if (i < OBD)  v = Wd[i - OWD];
    else if (i < NWF)  v = bd[i - OBD];
    ws[i] = v;
}

// One thread per batch element; weights in 22 VGPRs/lane, broadcast via SALU.
__global__ __launch_bounds__(256) void lstm3_fused(
    const float* __restrict__ x, const float* __restrict__ wpack,
    float* __restrict__ out, int B) {
    const int bidx = blockIdx.x * blockDim.x + threadIdx.x;
    const int lane = threadIdx.x & 63;

    // Load the entire weight set once: 22 coalesced dwords per lane.
    float w[NW];
#pragma unroll
    for (int k = 0; k < NW; ++k) w[k] = wpack[k * 64 + lane];

    if (bidx >= B) return;  // B % 256 == 0 in practice; guard is uniform

    const float* __restrict__ xb = x + (size_t)bidx * (SEQ * FEAT);
    float4* __restrict__ outb = (float4*)(out + (size_t)bidx * (SEQ * NOUT));

    float h1[NU1], c1[NU1], h2[NU2], c2[NU2], h3[NU3], c3[NU3];
#pragma unroll
    for (int u = 0; u < NU1; ++u) { h1[u] = 0.f; c1[u] = 0.f; }
#pragma unroll
    for (int u = 0; u < NU2; ++u) { h2[u] = 0.f; c2[u] = 0.f; }
#pragma unroll
    for (int u = 0; u < NU3; ++u) { h3[u] = 0.f; c3[u] = 0.f; }

    // Keep the body I$-resident; readlanes stay inside the loop (the asm
    // touch below blocks LICM from hoisting 1356 readlanes into SGPRs).
#pragma unroll 1
    for (int t = 0; t < SEQ; ++t) {
#pragma unroll
        for (int k = 0; k < NW; ++k) asm volatile("" : "+v"(w[k]));

        float xv[FEAT];
#pragma unroll
        for (int f = 0; f < FEAT; ++f) xv[f] = xb[t * FEAT + f];

        lstm_step<FEAT, NU1, OWK1, OWR1, OB1>(w, xv, h1, c1);
        lstm_step<NU1, NU2, OWK2, OWR2, OB2>(w, h1, h2, c2);
        lstm_step<NU2, NU3, OWK3, OWR3, OB3>(w, h2, h3, c3);

        // dense + sigmoid, 16B-aligned float4 store
        float od[NOUT];
#pragma unroll
        for (int o = 0; o < NOUT; ++o) {
            float z = getw(w, OBD + o);
#pragma unroll
            for (int u = 0; u < NU3; ++u)
                z = fmaf(h3[u], getw(w, OWD + u * NOUT + o), z);
            od[o] = sigm(z);
        }
        outb[t] = make_float4(od[0], od[1], od[2], od[3]);
    }
}

extern "C" void kernel_launch(void* const* d_in, const int* in_sizes, int n_in,
                              void* d_out, int out_size, void* d_ws, size_t ws_size,
                              hipStream_t stream) {
    const float* x   = (const float*)d_in[0];
    const float* Wk1 = (const float*)d_in[1];
    const float* Wr1 = (const float*)d_in[2];
    const float* b1  = (const float*)d_in[3];
    const float* Wk2 = (const float*)d_in[4];
    const float* Wr2 = (const float*)d_in[5];
    const float* b2  = (const float*)d_in[6];
    const float* Wk3 = (const float*)d_in[7];
    const float* Wr3 = (const float*)d_in[8];
    const float* b3  = (const float*)d_in[9];
    const float* Wd  = (const float*)d_in[10];
    const float* bd  = (const float*)d_in[11];
    float* out = (float*)d_out;
    float* ws  = (float*)d_ws;

    const int B = in_sizes[0] / (SEQ * FEAT);

    pack_weights<<<(NW * 64 + 255) / 256, 256, 0, stream>>>(
        Wk1, Wr1, b1, Wk2, Wr2, b2, Wk3, Wr3, b3, Wd, bd, ws);

    const int block = 256;
    const int grid = (B + block - 1) / block;
    lstm3_fused<<<grid, block, 0, stream>>>(x, ws, out, B);
}

// Round 4
// 423.402 us; speedup vs baseline: 1.5571x; 1.5571x over previous
//
#include <hip/hip_runtime.h>

// ---- problem constants ----
static constexpr int SEQ = 20, FEAT = 5, NU1 = 10, NU2 = 7, NU3 = 4, NOUT = 4;

// MFMA fragment types (per guide: short8 works for bf16 MFMA on gfx950)
typedef short bf16x8 __attribute__((ext_vector_type(8)));
typedef float f32x4  __attribute__((ext_vector_type(4)));

// ---- K-slot scheme ----
// Each logical input i occupies 4 K-slots: A=(Whi,Whi,Wlo,Wlo), B=(vhi,vlo,vhi,vlo)
// -> sum = (Whi+Wlo)(vhi+vlo): full fp32-class precision.
// Bias = extra input at i=I with A=(bhi,blo,0,0), B=(1,1,0,0).
// Layers (gate rows m: unit u=4*tau+(m>>2), gate=m&3, col=gate*U+u):
//  L1: I=15 (x:0..4, h1:5..14), bias i=15 -> 62 slots, 2 K-tiles, M-tiles 3
//  L2: I=17 (h1:0..9, h2:10..16), bias i=17 -> 70 slots, 3 K-tiles, M-tiles 2
//  L3: I=11 (h2:0..6, h3:7..10), bias i=11 -> 46 slots, 2 K-tiles, M-tiles 1
//  D : I=4  (h3), bias i=4 -> 18 slots, 1 K-tile, 1 M-tile (rows 0..3 = outputs)
// A-frag ids: L1: tau*2+kap (0..5); L2: 6+tau*3+kap (6..11); L3: 12+kap; D: 14.

// LDS staging per wave (bf16 slots, row n=elem 0..15), strides padded for
// even bank-window spread; all regions zeroed per group (=> h_0=0, and
// unused slots are exact zeros so A-zero columns can't meet NaN garbage):
//  L1: stride 176B (need 128B=2 K-tiles)  @ 0     (2816B)
//  L2: stride 208B (need 192B=3 K-tiles)  @ 2816  (3328B)
//  L3: stride 144B (need 128B)            @ 6144  (2304B)
//  D : stride 64B  (need 64B)             @ 8448  (1024B)
//  total 9472, padded region 9728B/wave, 4 waves/block = 38912B
static constexpr int WAVE_LDS = 9728;
static constexpr int OFF_L2 = 2816, OFF_L3 = 6144, OFF_D = 8448;

__device__ __forceinline__ unsigned short bf16_hi_rne(float x) {
    unsigned u = __float_as_uint(x);
    return (unsigned short)((u + 0x7FFF + ((u >> 16) & 1)) >> 16);
}
__device__ __forceinline__ unsigned short bf16_trunc(float x) {
    return (unsigned short)(__float_as_uint(x) >> 16);
}
__device__ __forceinline__ float bf16_to_f(unsigned short h) {
    return __uint_as_float(((unsigned)h) << 16);
}
// pack value as (hi | lo<<16): bf16 pair in memory order (hi at lower addr)
__device__ __forceinline__ unsigned hpack(float h) {
    unsigned u = __float_as_uint(h);
    unsigned r = (u + 0x7FFF + ((u >> 16) & 1)) >> 16;
    unsigned lo = __float_as_uint(h - __uint_as_float(r << 16)) >> 16;
    return r | (lo << 16);
}

__device__ __forceinline__ float sigm(float x) {
    return __builtin_amdgcn_rcpf(1.0f + __builtin_amdgcn_exp2f(x * -1.4426950408889634f));
}
__device__ __forceinline__ float ftanh(float x) {
    return 1.0f - 2.0f * __builtin_amdgcn_rcpf(1.0f + __builtin_amdgcn_exp2f(x * 2.8853900817779268f));
}

// z = (i,f,g,o) for one unit (lane-local); updates c, returns packed h (hi,lo)
__device__ __forceinline__ unsigned act_unit(const f32x4 z, float& c) {
    float gi = sigm(z[0]), gf = sigm(z[1]), gg = ftanh(z[2]), go = sigm(z[3]);
    c = gf * c + gi * gg;
    return hpack(go * ftanh(c));
}

// ---------- pre-kernel: build A-fragments into ws (15 frags x 64 lanes x 16B) ----------
__global__ void build_afrags(const float* Wk1, const float* Wr1, const float* b1,
                             const float* Wk2, const float* Wr2, const float* b2,
                             const float* Wk3, const float* Wr3, const float* b3,
                             const float* Wd,  const float* bd, unsigned* ws) {
    const int lane = threadIdx.x;  // 64 threads
    const int Us[3] = {NU1, NU2, NU3}, Is[3] = {15, 17, 11}, Ss[3] = {5, 10, 7};
    const float* Wa[3] = {Wk1, Wk2, Wk3};
    const float* Wb[3] = {Wr1, Wr2, Wr3};
    const float* bs[3] = {b1, b2, b3};
    const int baseid[3] = {0, 6, 12}, KT[3] = {2, 3, 2}, MT[3] = {3, 2, 1};
    for (int L = 0; L < 3; ++L) {
        const int U = Us[L], I = Is[L], Sp = Ss[L];
        for (int tau = 0; tau < MT[L]; ++tau)
        for (int kap = 0; kap < KT[L]; ++kap) {
            const int id = baseid[L] + tau * KT[L] + kap;
            unsigned short h8[8];
            for (int j = 0; j < 8; ++j) {
                const int m = lane & 15;
                const int k = kap * 32 + (lane >> 4) * 8 + j;
                const int i = k >> 2, cls = k & 3;
                const int u = tau * 4 + (m >> 2), g = m & 3, col = g * U + u;
                unsigned short v = 0;
                if (u < U) {
                    if (i < I) {
                        float W = (i < Sp) ? Wa[L][i * 4 * U + col]
                                           : Wb[L][(i - Sp) * 4 * U + col];
                        unsigned short hi = bf16_hi_rne(W);
                        v = (cls < 2) ? hi : bf16_trunc(W - bf16_to_f(hi));
                    } else if (i == I) {
                        float bv = bs[L][col];
                        unsigned short hi = bf16_hi_rne(bv);
                        v = (cls == 0) ? hi : ((cls == 1) ? bf16_trunc(bv - bf16_to_f(hi)) : (unsigned short)0);
                    }
                }
                h8[j] = v;
            }
            for (int d = 0; d < 4; ++d)
                ws[id * 256 + lane * 4 + d] = (unsigned)h8[2 * d] | ((unsigned)h8[2 * d + 1] << 16);
        }
    }
    {   // dense: id 14, rows m=0..3 are outputs; I=4 (h3), bias i=4
        unsigned short h8[8];
        for (int j = 0; j < 8; ++j) {
            const int m = lane & 15;
            const int k = (lane >> 4) * 8 + j;
            const int i = k >> 2, cls = k & 3;
            unsigned short v = 0;
            if (m < NOUT) {
                if (i < 4) {
                    float W = Wd[i * NOUT + m];
                    unsigned short hi = bf16_hi_rne(W);
                    v = (cls < 2) ? hi : bf16_trunc(W - bf16_to_f(hi));
                } else if (i == 4) {
                    float bv = bd[m];
                    unsigned short hi = bf16_hi_rne(bv);
                    v = (cls == 0) ? hi : ((cls == 1) ? bf16_trunc(bv - bf16_to_f(hi)) : (unsigned short)0);
                }
            }
            h8[j] = v;
        }
        for (int d = 0; d < 4; ++d)
            ws[14 * 256 + lane * 4 + d] = (unsigned)h8[2 * d] | ((unsigned)h8[2 * d + 1] << 16);
    }
}

// ---------- main kernel: 16 batch elems per wave, wave-private LDS staging ----------
__global__ __launch_bounds__(256, 3) void lstm3_mfma(
    const float* __restrict__ x, const unsigned* __restrict__ wsA,
    float* __restrict__ out, int B) {
    __shared__ __attribute__((aligned(16))) char lds_raw[4 * WAVE_LDS];
    const int tid = threadIdx.x;
    const int lane = tid & 63;
    const int n = lane & 15;        // batch elem within group (= B/C col)
    const int q = lane >> 4;        // K-quad (B operand) / unit-quad (C)
    char* S  = lds_raw + (tid >> 6) * WAVE_LDS;
    char* L1 = S;
    char* L2 = S + OFF_L2;
    char* L3 = S + OFF_L3;
    char* SD = S + OFF_D;

    // A-fragments: 15 x 16B per lane, coalesced
    bf16x8 af[15];
#pragma unroll
    for (int i = 0; i < 15; ++i) {
        uint4 v = ((const uint4*)wsA)[i * 64 + lane];
        af[i] = __builtin_bit_cast(bf16x8, v);
    }

    // precomputed lane addresses
    char* rB1 = L1 + n * 176 + 16 * q;            // +64*kap
    char* rB2 = L2 + n * 208 + 16 * q;
    char* rB3 = L3 + n * 144 + 16 * q;
    char* rBD = SD + n * 64 + 16 * q;
    char* wL1s = L1 + n * 176 + 40 + 8 * q;       // h1 self   (+32*tau)
    char* wL2a = L2 + n * 208 + 8 * q;            // h1 -> L2  (+32*tau)
    char* wL2s = L2 + n * 208 + 80 + 8 * q;       // h2 self   (+32*tau)
    char* wL3a = L3 + n * 144 + 8 * q;            // h2 -> L3  (+32*tau)
    char* wL3s = L3 + n * 144 + 56 + 8 * q;       // h3 self
    char* wDa  = SD + n * 64 + 8 * q;             // h3 -> D
    char* wx1  = L1 + (lane >> 2) * 176 + 8 * (lane & 3);
    char* wx2  = L1 + lane * 176 + 32;            // f=4, lanes<16

    const int ngrp = B >> 4;
    const int gw = (blockIdx.x * blockDim.x + tid) >> 6;
    const int nw = (gridDim.x * blockDim.x) >> 6;

    for (int grp = gw; grp < ngrp; grp += nw) {
        // zero whole staging (=> h_0 = 0 and NaN-proof padding)
#pragma unroll
        for (int i = 0; i < 9; ++i) *(uint4*)(S + i * 1024 + lane * 16) = uint4{0, 0, 0, 0};
        if (lane < 32) *(uint4*)(S + 9 * 1024 + lane * 16) = uint4{0, 0, 0, 0};
        // constant-1.0 B slots for the bias input
        if (lane < 16) {
            *(unsigned*)(L1 + lane * 176 + 120) = 0x3F803F80u;  // k=60,61
            *(unsigned*)(L2 + lane * 208 + 136) = 0x3F803F80u;  // k=68,69
            *(unsigned*)(L3 + lane * 144 + 88)  = 0x3F803F80u;  // k=44,45
            *(unsigned*)(SD + lane * 64 + 32)   = 0x3F803F80u;  // k=16,17
        }

        float c10 = 0.f, c11 = 0.f, c12 = 0.f, c20 = 0.f, c21 = 0.f, c30 = 0.f;
        const float* xb = x + (size_t)grp * 16 * (SEQ * FEAT);
        float* ob = out + (size_t)grp * 16 * (SEQ * NOUT);

#pragma unroll 1
        for (int t = 0; t < SEQ; ++t) {
            // ---- stage x_t (slots k=4f..4f+3) ----
            {
                float xv = xb[(lane >> 2) * 100 + t * 5 + (lane & 3)];
                unsigned p = hpack(xv);
                *(uint2*)wx1 = uint2{p, p};
                if (lane < 16) {
                    float x4 = xb[lane * 100 + t * 5 + 4];
                    unsigned p2 = hpack(x4);
                    *(uint2*)wx2 = uint2{p2, p2};
                }
            }
            // ---- L1: Z^T = Wcat1^T * [x;h1;1]^T ----
            bf16x8 b0 = *(const bf16x8*)(rB1);
            bf16x8 b1v = *(const bf16x8*)(rB1 + 64);
            f32x4 z0 = {0, 0, 0, 0}, z1 = {0, 0, 0, 0}, z2 = {0, 0, 0, 0};
            z0 = __builtin_amdgcn_mfma_f32_16x16x32_bf16(af[0], b0,  z0, 0, 0, 0);
            z0 = __builtin_amdgcn_mfma_f32_16x16x32_bf16(af[1], b1v, z0, 0, 0, 0);
            z1 = __builtin_amdgcn_mfma_f32_16x16x32_bf16(af[2], b0,  z1, 0, 0, 0);
            z1 = __builtin_amdgcn_mfma_f32_16x16x32_bf16(af[3], b1v, z1, 0, 0, 0);
            z2 = __builtin_amdgcn_mfma_f32_16x16x32_bf16(af[4], b0,  z2, 0, 0, 0);
            z2 = __builtin_amdgcn_mfma_f32_16x16x32_bf16(af[5], b1v, z2, 0, 0, 0);
            {
                unsigned p = act_unit(z0, c10);           // units 0..3
                *(uint2*)(wL1s + 0) = uint2{p, p};
                *(uint2*)(wL2a + 0) = uint2{p, p};
                p = act_unit(z1, c11);                    // units 4..7
                *(uint2*)(wL1s + 32) = uint2{p, p};
                *(uint2*)(wL2a + 32) = uint2{p, p};
                p = act_unit(z2, c12);                    // units 8..9 (q<2)
                if (q < 2) {
                    *(uint2*)(wL1s + 64) = uint2{p, p};
                    *(uint2*)(wL2a + 64) = uint2{p, p};
                }
            }
            // ---- L2 ----
            bf16x8 c0 = *(const bf16x8*)(rB2);
            bf16x8 c1v = *(const bf16x8*)(rB2 + 64);
            bf16x8 c2v = *(const bf16x8*)(rB2 + 128);
            f32x4 y0 = {0, 0, 0, 0}, y1 = {0, 0, 0, 0};
            y0 = __builtin_amdgcn_mfma_f32_16x16x32_bf16(af[6],  c0,  y0, 0, 0, 0);
            y0 = __builtin_amdgcn_mfma_f32_16x16x32_bf16(af[7],  c1v, y0, 0, 0, 0);
            y0 = __builtin_amdgcn_mfma_f32_16x16x32_bf16(af[8],  c2v, y0, 0, 0, 0);
            y1 = __builtin_amdgcn_mfma_f32_16x16x32_bf16(af[9],  c0,  y1, 0, 0, 0);
            y1 = __builtin_amdgcn_mfma_f32_16x16x32_bf16(af[10], c1v, y1, 0, 0, 0);
            y1 = __builtin_amdgcn_mfma_f32_16x16x32_bf16(af[11], c2v, y1, 0, 0, 0);
            {
                unsigned p = act_unit(y0, c20);           // units 0..3
                *(uint2*)(wL2s + 0) = uint2{p, p};
                *(uint2*)(wL3a + 0) = uint2{p, p};
                p = act_unit(y1, c21);                    // units 4..6 (q<3)
                if (q < 3) {
                    *(uint2*)(wL2s + 32) = uint2{p, p};
                    *(uint2*)(wL3a + 32) = uint2{p, p};
                }
            }
            // ---- L3 ----
            bf16x8 d0v = *(const bf16x8*)(rB3);
            bf16x8 d1v = *(const bf16x8*)(rB3 + 64);
            f32x4 w0 = {0, 0, 0, 0};
            w0 = __builtin_amdgcn_mfma_f32_16x16x32_bf16(af[12], d0v, w0, 0, 0, 0);
            w0 = __builtin_amdgcn_mfma_f32_16x16x32_bf16(af[13], d1v, w0, 0, 0, 0);
            {
                unsigned p = act_unit(w0, c30);           // units 0..3
                *(uint2*)wL3s = uint2{p, p};
                *(uint2*)wDa  = uint2{p, p};
            }
            // ---- dense + sigmoid + store ----
            bf16x8 e0 = *(const bf16x8*)(rBD);
            f32x4 o0 = {0, 0, 0, 0};
            o0 = __builtin_amdgcn_mfma_f32_16x16x32_bf16(af[14], e0, o0, 0, 0, 0);
            if (lane < 16) {
                float4 o4;
                o4.x = sigm(o0[0]); o4.y = sigm(o0[1]);
                o4.z = sigm(o0[2]); o4.w = sigm(o0[3]);
                *(float4*)(ob + lane * (SEQ * NOUT) + t * NOUT) = o4;
            }
        }
    }
}

extern "C" void kernel_launch(void* const* d_in, const int* in_sizes, int n_in,
                              void* d_out, int out_size, void* d_ws, size_t ws_size,
                              hipStream_t stream) {
    const float* x   = (const float*)d_in[0];
    const float* Wk1 = (const float*)d_in[1];
    const float* Wr1 = (const float*)d_in[2];
    const float* b1  = (const float*)d_in[3];
    const float* Wk2 = (const float*)d_in[4];
    const float* Wr2 = (const float*)d_in[5];
    const float* b2  = (const float*)d_in[6];
    const float* Wk3 = (const float*)d_in[7];
    const float* Wr3 = (const float*)d_in[8];
    const float* b3  = (const float*)d_in[9];
    const float* Wd  = (const float*)d_in[10];
    const float* bd  = (const float*)d_in[11];
    float* out = (float*)d_out;
    unsigned* ws = (unsigned*)d_ws;

    const int B = in_sizes[0] / (SEQ * FEAT);

    build_afrags<<<1, 64, 0, stream>>>(Wk1, Wr1, b1, Wk2, Wr2, b2,
                                       Wk3, Wr3, b3, Wd, bd, ws);
    lstm3_mfma<<<1024, 256, 0, stream>>>(x, ws, out, B);
}